// Round 8
// baseline (2764.519 us; speedup 1.0000x reference)
//
#include <hip/hip_runtime.h>
#include <hip/hip_bf16.h>

#define D_MODEL 4096
#define D_FF    11008
#define NTOK    4096   // 2*2048 tokens

typedef __attribute__((ext_vector_type(8))) short short8;
typedef __attribute__((ext_vector_type(4))) float f32x4;

// ---------------- fp32 -> bf16 convert (8 elems/thread) — X only --------
__global__ void k_cvt(const float* __restrict__ in, __hip_bfloat16* __restrict__ out, int n8) {
    int i = blockIdx.x * blockDim.x + threadIdx.x;
    if (i >= n8) return;
    const float4* p = (const float4*)in;
    float4 v0 = p[(size_t)i * 2];
    float4 v1 = p[(size_t)i * 2 + 1];
    float vals[8] = {v0.x, v0.y, v0.z, v0.w, v1.x, v1.y, v1.z, v1.w};
    short8 o;
#pragma unroll
    for (int j = 0; j < 8; ++j) {
        __hip_bfloat16 b = __float2bfloat16(vals[j]);
        o[j] = *reinterpret_cast<short*>(&b);
    }
    *reinterpret_cast<short8*>(out + (size_t)i * 8) = o;
}

// ---- stage one 128x64 bf16 half-tile via global_load_lds (A operand) ----
// LDS dest linear; swizzle via permuted GLOBAL source chunk (rule #21):
// physical chunk p of row r holds logical chunk p ^ (r&7).
static __device__ __forceinline__ void stage_half(
    const __hip_bfloat16* g, int ld, __hip_bfloat16* lds, int tid)
{
#pragma unroll
    for (int s = 0; s < 2; ++s) {
        int ci = s * 512 + tid;            // 16B chunk 0..1023
        int r  = ci >> 3;                  // row 0..127
        int c  = (ci & 7) ^ (r & 7);       // logical chunk
        __builtin_amdgcn_global_load_lds(
            (const __attribute__((address_space(1))) void*)(g + (long)r * ld + c * 8),
            (__attribute__((address_space(3))) void*)(lds + ci * 8),
            16, 0, 0);
    }
}
// swizzled LDS read offset (row within 128-row half, kb = col, multiple of 8)
static __device__ __forceinline__ int sw_off(int row, int kb) {
    return row * 64 + ((((kb >> 3) ^ (row & 7))) << 3);
}

// ---- W reg-staging: load 2x(128x64) f32 halves into 16 f32x4 regs ------
// Same chunk->global mapping as stage_half (so the ds_write below lands the
// identical swizzled layout). 8 dwordx4 loads per call.
#define LOADW(wreg, P0, P1, KOFF)                                              \
    _Pragma("unroll")                                                          \
    for (int q = 0; q < 2; ++q) {                                              \
        const float* srcw = ((q == 0) ? (P0) : (P1)) + (KOFF);                 \
        _Pragma("unroll")                                                      \
        for (int s = 0; s < 2; ++s) {                                          \
            int ci = s * 512 + tid;                                            \
            int rr = ci >> 3, cc = (ci & 7) ^ (rr & 7);                        \
            const f32x4* gp = reinterpret_cast<const f32x4*>(                  \
                srcw + (long)rr * K + cc * 8);                                 \
            wreg[q * 4 + s * 2 + 0] = gp[0];                                   \
            wreg[q * 4 + s * 2 + 1] = gp[1];                                   \
        }                                                                      \
    }

// ---- cvt f32->bf16 + ds_write_b128 x4 into [h0 | h1(+8192)] layout -----
#define WRITEW(wreg, ldsbase)                                                  \
    _Pragma("unroll")                                                          \
    for (int q = 0; q < 2; ++q)                                                \
        _Pragma("unroll")                                                      \
        for (int s = 0; s < 2; ++s) {                                          \
            int ci = s * 512 + tid;                                            \
            short8 pk;                                                         \
            _Pragma("unroll")                                                  \
            for (int e = 0; e < 4; ++e) {                                      \
                __hip_bfloat16 b0 = __float2bfloat16(wreg[q*4+s*2+0][e]);      \
                __hip_bfloat16 b1 = __float2bfloat16(wreg[q*4+s*2+1][e]);      \
                pk[e]     = *reinterpret_cast<short*>(&b0);                    \
                pk[4 + e] = *reinterpret_cast<short*>(&b1);                    \
            }                                                                  \
            *reinterpret_cast<short8*>((ldsbase) + (q ? 8192 : 0) + ci * 8) = pk; \
        }

#define MFMA16(a, b, c) __builtin_amdgcn_mfma_f32_16x16x32_bf16(a, b, c, 0, 0, 0)
#define VMW(pfflag) do { if (pfflag) asm volatile("s_waitcnt vmcnt(8)" ::: "memory"); \
                         else        asm volatile("s_waitcnt vmcnt(0)" ::: "memory"); } while (0)

// ============ fused gate+up: H = silu(X Wg^T) * (X Wu^T) ================
// 8-phase / 2 K-tile schedule. A = X bf16 via gload_lds (ph1-2 / 5-6).
// B = [G|U] reg-staged from f32: loads at ph3 (wA=W(t+2)) / ph7 (wB=W(t+3)),
// cvt+ds_write at ph8 (wA->bufB0) / ph4 (wB->bufB1). vmcnt(8) at ph4/ph8.
#define FPHASE(cA, cB, IQ, LOADB, STAGE)                                       \
    {                                                                          \
        short8 af[2][2];                                                       \
        _Pragma("unroll")                                                      \
        for (int ii = 0; ii < 2; ++ii)                                         \
            _Pragma("unroll")                                                  \
            for (int kk = 0; kk < 2; ++kk)                                     \
                af[ii][kk] = *reinterpret_cast<const short8*>(                 \
                    &(cA)[sw_off(wm * 128 + ((IQ) * 2 + ii) * 16 + r16,        \
                                 kk * 32 + g4 * 8)]);                          \
        if (LOADB) {                                                           \
            _Pragma("unroll")                                                  \
            for (int kk = 0; kk < 2; ++kk)                                     \
                _Pragma("unroll")                                              \
                for (int j = 0; j < 2; ++j) {                                  \
                    bg[kk][j] = *reinterpret_cast<const short8*>(              \
                        &(cB)[sw_off(wn * 32 + j * 16 + r16,                   \
                                     kk * 32 + g4 * 8)]);                      \
                    bu[kk][j] = *reinterpret_cast<const short8*>(              \
                        &(cB)[8192 + sw_off(wn * 32 + j * 16 + r16,            \
                                            kk * 32 + g4 * 8)]);               \
                }                                                              \
        }                                                                      \
        STAGE;                                                                 \
        if (LOADB) asm volatile("s_waitcnt lgkmcnt(8)" ::: "memory");          \
        __builtin_amdgcn_s_barrier();                                          \
        asm volatile("s_waitcnt lgkmcnt(0)" ::: "memory");                     \
        __builtin_amdgcn_sched_barrier(0);                                     \
        __builtin_amdgcn_s_setprio(1);                                         \
        _Pragma("unroll")                                                      \
        for (int ii = 0; ii < 2; ++ii)                                         \
            _Pragma("unroll")                                                  \
            for (int j = 0; j < 2; ++j) {                                      \
                accg[(IQ) * 2 + ii][j] = MFMA16(af[ii][0], bg[0][j],           \
                                                accg[(IQ) * 2 + ii][j]);       \
                accg[(IQ) * 2 + ii][j] = MFMA16(af[ii][1], bg[1][j],           \
                                                accg[(IQ) * 2 + ii][j]);       \
                accu[(IQ) * 2 + ii][j] = MFMA16(af[ii][0], bu[0][j],           \
                                                accu[(IQ) * 2 + ii][j]);       \
                accu[(IQ) * 2 + ii][j] = MFMA16(af[ii][1], bu[1][j],           \
                                                accu[(IQ) * 2 + ii][j]);       \
            }                                                                  \
        __builtin_amdgcn_s_setprio(0);                                         \
        __builtin_amdgcn_sched_barrier(0);                                     \
        __builtin_amdgcn_s_barrier();                                          \
    }

__global__ __launch_bounds__(512, 2)
void k_gateup(const __hip_bfloat16* __restrict__ X,
              const float* __restrict__ Wg,
              const float* __restrict__ Wu,
              __hip_bfloat16* __restrict__ H)
{
    extern __shared__ __hip_bfloat16 smem[];
    __hip_bfloat16* sA = smem;           // [2 buf][256 rows][64] = 64 KB
    __hip_bfloat16* sB = smem + 32768;   // [2 buf][G 128x64 | U 128x64] = 64 KB

    const int tid  = threadIdx.x;
    const int lane = tid & 63;
    const int wid  = tid >> 6;
    const int wm = wid >> 2, wn = wid & 3;   // 2M x 4N waves
    const int r16 = lane & 15, g4 = lane >> 4;

    // T1: bijective XCD chunks (1376 = 8*172), m-fastest inside chunk
    const int bid = blockIdx.x;
    const int o = (bid & 7) * 172 + (bid >> 3);
    const int n0 = (o >> 4) * 128;
    const int m0 = (o & 15) * 256;

    const int K = D_MODEL;
    const __hip_bfloat16* Ab = X + (long)m0 * K;
    const float* G32 = Wg + (long)n0 * K;
    const float* U32 = Wu + (long)n0 * K;
    const long h1 = (long)128 * K;

    f32x4 wA[8], wB[8];

    // prologue: A(0) gl_lds; W(0) -> regs -> write bufB0; W(1) -> wB in flight
    stage_half(Ab,      K, sA + 0,    tid);
    stage_half(Ab + h1, K, sA + 8192, tid);
    LOADW(wA, G32, U32, 0)
    asm volatile("s_waitcnt vmcnt(0)" ::: "memory");
    WRITEW(wA, sB)
    LOADW(wB, G32, U32, 64)
    asm volatile("s_waitcnt lgkmcnt(0)" ::: "memory");
    __builtin_amdgcn_s_barrier();

    f32x4 accg[8][2], accu[8][2];
#pragma unroll
    for (int i = 0; i < 8; ++i)
#pragma unroll
        for (int j = 0; j < 2; ++j) {
            accg[i][j] = (f32x4){0.f, 0.f, 0.f, 0.f};
            accu[i][j] = (f32x4){0.f, 0.f, 0.f, 0.f};
        }

    const int nk = K >> 6;        // 64
    const int niter = nk >> 1;    // 32

    for (int it = 0; it < niter; ++it) {
        const bool pf = (it + 1 < niter);
        const long kA1 = (long)(2 * it + 1) * 64;
        const long kA2 = (long)(2 * it + 2) * 64;
        const long kW2 = (long)(2 * it + 2) * 64;   // f32 col offset
        const long kW3 = (long)(2 * it + 3) * 64;
        short8 bg[2][2], bu[2][2];
        {   // phases 1-4: K-tile 2it from buf0
            const __hip_bfloat16* cA = sA;
            const __hip_bfloat16* cB = sB;
            FPHASE(cA, cB, 0, 1, stage_half(Ab + kA1,      K, sA + 16384,        tid));
            FPHASE(cA, cB, 1, 0, stage_half(Ab + h1 + kA1, K, sA + 16384 + 8192, tid));
            FPHASE(cA, cB, 2, 0, if (pf) LOADW(wA, G32, U32, kW2));
            FPHASE(cA, cB, 3, 0, { VMW(pf); WRITEW(wB, sB + 16384) });
        }
        {   // phases 5-8: K-tile 2it+1 from buf1
            const __hip_bfloat16* cA = sA + 16384;
            const __hip_bfloat16* cB = sB + 16384;
            FPHASE(cA, cB, 0, 1, if (pf) stage_half(Ab + kA2,      K, sA + 0,    tid));
            FPHASE(cA, cB, 1, 0, if (pf) stage_half(Ab + h1 + kA2, K, sA + 8192, tid));
            FPHASE(cA, cB, 2, 0, if (pf) LOADW(wB, G32, U32, kW3));
            FPHASE(cA, cB, 3, 0, { if (pf) { VMW(true); WRITEW(wA, sB) } });
        }
    }

    // epilogue: h = silu(g) * u
#pragma unroll
    for (int i = 0; i < 8; ++i)
#pragma unroll
        for (int j = 0; j < 2; ++j)
#pragma unroll
            for (int r = 0; r < 4; ++r) {
                long row = m0 + wm * 128 + i * 16 + g4 * 4 + r;
                long col = n0 + wn * 32 + j * 16 + r16;
                float g = accg[i][j][r];
                float u = accu[i][j][r];
                float s = g / (1.f + __expf(-g));
                H[row * D_FF + col] = __float2bfloat16(s * u);
            }
}

// ================= down proj: Y = H Wd^T (f32 out) ======================
// Same v-schedule: A = H bf16 gload_lds; B = Wd reg-staged from f32.
#define DPHASE(cA, cB, IQ, LOADB, STAGE)                                       \
    {                                                                          \
        short8 af[2][2];                                                       \
        _Pragma("unroll")                                                      \
        for (int ii = 0; ii < 2; ++ii)                                         \
            _Pragma("unroll")                                                  \
            for (int kk = 0; kk < 2; ++kk)                                     \
                af[ii][kk] = *reinterpret_cast<const short8*>(                 \
                    &(cA)[sw_off(wm * 128 + ((IQ) * 2 + ii) * 16 + r16,        \
                                 kk * 32 + g4 * 8)]);                          \
        if (LOADB) {                                                           \
            _Pragma("unroll")                                                  \
            for (int kk = 0; kk < 2; ++kk)                                     \
                _Pragma("unroll")                                              \
                for (int j = 0; j < 4; ++j)                                    \
                    bfr[kk][j] = *reinterpret_cast<const short8*>(             \
                        &(cB)[sw_off(wn * 64 + j * 16 + r16,                   \
                                     kk * 32 + g4 * 8)]);                      \
        }                                                                      \
        STAGE;                                                                 \
        if (LOADB) asm volatile("s_waitcnt lgkmcnt(8)" ::: "memory");          \
        __builtin_amdgcn_s_barrier();                                          \
        asm volatile("s_waitcnt lgkmcnt(0)" ::: "memory");                     \
        __builtin_amdgcn_sched_barrier(0);                                     \
        __builtin_amdgcn_s_setprio(1);                                         \
        _Pragma("unroll")                                                      \
        for (int ii = 0; ii < 2; ++ii)                                         \
            _Pragma("unroll")                                                  \
            for (int j = 0; j < 4; ++j) {                                      \
                acc[(IQ) * 2 + ii][j] = MFMA16(af[ii][0], bfr[0][j],           \
                                               acc[(IQ) * 2 + ii][j]);         \
                acc[(IQ) * 2 + ii][j] = MFMA16(af[ii][1], bfr[1][j],           \
                                               acc[(IQ) * 2 + ii][j]);         \
            }                                                                  \
        __builtin_amdgcn_s_setprio(0);                                         \
        __builtin_amdgcn_sched_barrier(0);                                     \
        __builtin_amdgcn_s_barrier();                                          \
    }

__global__ __launch_bounds__(512, 2)
void k_down(const __hip_bfloat16* __restrict__ A,
            const float* __restrict__ Wd,
            float* __restrict__ Y)
{
    extern __shared__ __hip_bfloat16 smem[];
    __hip_bfloat16* sA = smem;           // [2 buf][256][64]
    __hip_bfloat16* sB = smem + 32768;   // [2 buf][rows 0-127 | rows 128-255]

    const int tid  = threadIdx.x;
    const int lane = tid & 63;
    const int wid  = tid >> 6;
    const int wm = wid >> 2, wn = wid & 3;
    const int r16 = lane & 15, g4 = lane >> 4;

    const int bid = blockIdx.x;          // 256 = 8*32
    const int o = (bid & 7) * 32 + (bid >> 3);
    const int n0 = (o >> 4) << 8;
    const int m0 = (o & 15) << 8;

    const int K = D_FF;
    const int N = D_MODEL;
    const __hip_bfloat16* Ab = A + (long)m0 * K;
    const float* B032 = Wd + (long)n0 * K;
    const float* B132 = Wd + (long)(n0 + 128) * K;
    const long h1 = (long)128 * K;

    f32x4 wA[8], wB[8];

    stage_half(Ab,      K, sA + 0,    tid);
    stage_half(Ab + h1, K, sA + 8192, tid);
    LOADW(wA, B032, B132, 0)
    asm volatile("s_waitcnt vmcnt(0)" ::: "memory");
    WRITEW(wA, sB)
    LOADW(wB, B032, B132, 64)
    asm volatile("s_waitcnt lgkmcnt(0)" ::: "memory");
    __builtin_amdgcn_s_barrier();

    f32x4 acc[8][4];
#pragma unroll
    for (int i = 0; i < 8; ++i)
#pragma unroll
        for (int j = 0; j < 4; ++j)
            acc[i][j] = (f32x4){0.f, 0.f, 0.f, 0.f};

    const int nk = K >> 6;        // 172
    const int niter = nk >> 1;    // 86

    for (int it = 0; it < niter; ++it) {
        const bool pf = (it + 1 < niter);
        const long kA1 = (long)(2 * it + 1) * 64;
        const long kA2 = (long)(2 * it + 2) * 64;
        const long kW2 = (long)(2 * it + 2) * 64;
        const long kW3 = (long)(2 * it + 3) * 64;
        short8 bfr[2][4];
        {
            const __hip_bfloat16* cA = sA;
            const __hip_bfloat16* cB = sB;
            DPHASE(cA, cB, 0, 1, stage_half(Ab + kA1,      K, sA + 16384,        tid));
            DPHASE(cA, cB, 1, 0, stage_half(Ab + h1 + kA1, K, sA + 16384 + 8192, tid));
            DPHASE(cA, cB, 2, 0, if (pf) LOADW(wA, B032, B132, kW2));
            DPHASE(cA, cB, 3, 0, { VMW(pf); WRITEW(wB, sB + 16384) });
        }
        {
            const __hip_bfloat16* cA = sA + 16384;
            const __hip_bfloat16* cB = sB + 16384;
            DPHASE(cA, cB, 0, 1, if (pf) stage_half(Ab + kA2,      K, sA + 0,    tid));
            DPHASE(cA, cB, 1, 0, if (pf) stage_half(Ab + h1 + kA2, K, sA + 8192, tid));
            DPHASE(cA, cB, 2, 0, if (pf) LOADW(wB, B032, B132, kW3));
            DPHASE(cA, cB, 3, 0, { if (pf) { VMW(true); WRITEW(wA, sB) } });
        }
    }

#pragma unroll
    for (int i = 0; i < 8; ++i)
#pragma unroll
        for (int j = 0; j < 4; ++j)
#pragma unroll
            for (int r = 0; r < 4; ++r) {
                long row = m0 + wm * 128 + i * 16 + g4 * 4 + r;
                long col = n0 + wn * 64 + j * 16 + r16;
                Y[row * N + col] = acc[i][j][r];
            }
}

extern "C" void kernel_launch(void* const* d_in, const int* in_sizes, int n_in,
                              void* d_out, int out_size, void* d_ws, size_t ws_size,
                              hipStream_t stream) {
    const float* x  = (const float*)d_in[0];
    const float* wg = (const float*)d_in[1];
    const float* wu = (const float*)d_in[2];
    const float* wd = (const float*)d_in[3];
    float* y = (float*)d_out;

    char* ws = (char*)d_ws;
    const size_t szX = (size_t)NTOK * D_MODEL * 2;
    __hip_bfloat16* Xb = (__hip_bfloat16*)(ws);
    __hip_bfloat16* Hb = (__hip_bfloat16*)(ws + szX);
    (void)ws_size; (void)out_size; (void)n_in; (void)in_sizes;

    const int SMEM = 131072;  // 128 KiB for both GEMMs
    hipFuncSetAttribute((const void*)k_gateup, hipFuncAttributeMaxDynamicSharedMemorySize, SMEM);
    hipFuncSetAttribute((const void*)k_down,   hipFuncAttributeMaxDynamicSharedMemorySize, SMEM);

    const int nX = NTOK * D_MODEL / 8;
    k_cvt<<<(nX + 255) / 256, 256, 0, stream>>>(x, Xb, nX);

    // fused: Hb = silu(X Wg^T) * (X Wu^T)   (W read as f32, cvt in staging)
    k_gateup<<<1376, 512, SMEM, stream>>>(Xb, wg, wu, Hb);
    // down:  Y = Hb Wd^T (f32 out)
    k_down<<<256, 512, SMEM, stream>>>(Hb, wd, y);
}

// Round 9
// 1045.425 us; speedup vs baseline: 2.6444x; 2.6444x over previous
//
#include <hip/hip_runtime.h>
#include <hip/hip_bf16.h>

#define D_MODEL 4096
#define D_FF    11008
#define NTOK    4096   // 2*2048 tokens
#define LDP     4160   // padded row stride (elems) for K=4096 operands:
                       // 8320 B = 130 x 64B lines, breaks pow2 channel aliasing

typedef __attribute__((ext_vector_type(8))) short short8;
typedef __attribute__((ext_vector_type(4))) float f32x4;

// ------- fp32 -> bf16 convert, linear (Wd: K=11008 rows not padded) -----
__global__ void k_cvt(const float* __restrict__ in, __hip_bfloat16* __restrict__ out, int n8) {
    int i = blockIdx.x * blockDim.x + threadIdx.x;
    if (i >= n8) return;
    const float4* p = (const float4*)in;
    float4 v0 = p[(size_t)i * 2];
    float4 v1 = p[(size_t)i * 2 + 1];
    float vals[8] = {v0.x, v0.y, v0.z, v0.w, v1.x, v1.y, v1.z, v1.w};
    short8 o;
#pragma unroll
    for (int j = 0; j < 8; ++j) {
        __hip_bfloat16 b = __float2bfloat16(vals[j]);
        o[j] = *reinterpret_cast<short*>(&b);
    }
    *reinterpret_cast<short8*>(out + (size_t)i * 8) = o;
}

// ------- fp32 -> bf16 convert with padded output stride (K=4096 rows) ---
// input rows of 4096 f32 (512 chunks of 8); output rows of LDP bf16.
__global__ void k_cvt_pad(const float* __restrict__ in, __hip_bfloat16* __restrict__ out, int n8) {
    int i = blockIdx.x * blockDim.x + threadIdx.x;
    if (i >= n8) return;
    int row = i >> 9;          // 512 chunks per row
    int c8  = i & 511;
    const float4* p = (const float4*)(in + (size_t)row * 4096 + c8 * 8);
    float4 v0 = p[0];
    float4 v1 = p[1];
    float vals[8] = {v0.x, v0.y, v0.z, v0.w, v1.x, v1.y, v1.z, v1.w};
    short8 o;
#pragma unroll
    for (int j = 0; j < 8; ++j) {
        __hip_bfloat16 b = __float2bfloat16(vals[j]);
        o[j] = *reinterpret_cast<short*>(&b);
    }
    *reinterpret_cast<short8*>(out + (size_t)row * LDP + c8 * 8) = o;
}

// ---- stage one 128x64 bf16 half-tile via global_load_lds ----
// LDS dest linear; swizzle via permuted GLOBAL source chunk (rule #21):
// physical chunk p of row r holds logical chunk p ^ (r&7).
static __device__ __forceinline__ void stage_half(
    const __hip_bfloat16* g, int ld, __hip_bfloat16* lds, int tid)
{
#pragma unroll
    for (int s = 0; s < 2; ++s) {
        int ci = s * 512 + tid;            // 16B chunk 0..1023
        int r  = ci >> 3;                  // row 0..127
        int c  = (ci & 7) ^ (r & 7);       // logical chunk
        __builtin_amdgcn_global_load_lds(
            (const __attribute__((address_space(1))) void*)(g + (long)r * ld + c * 8),
            (__attribute__((address_space(3))) void*)(lds + ci * 8),
            16, 0, 0);
    }
}
// swizzled LDS read offset (row within 128-row half, kb = col, multiple of 8)
static __device__ __forceinline__ int sw_off(int row, int kb) {
    return row * 64 + ((((kb >> 3) ^ (row & 7))) << 3);
}

#define MFMA16(a, b, c) __builtin_amdgcn_mfma_f32_16x16x32_bf16(a, b, c, 0, 0, 0)
#define VM4D do { if (pf) asm volatile("s_waitcnt vmcnt(4)" ::: "memory");     \
                  else    asm volatile("s_waitcnt vmcnt(0)" ::: "memory"); } while (0)

// ============ fused gate+up: H = silu(X Wg^T) * (X Wu^T) ================
// 8-phase / 2 K-tile schedule; A = X (256x64 dbuf), B = [G|U] dbuf.
// A staged ph1-2/5-6, B staged ph3-4/7-8, vmcnt(4) at ph4/ph8.
#define FPHASE(cA, cB, IQ, LOADB, STAGE, VMC)                                  \
    {                                                                          \
        short8 af[2][2];                                                       \
        _Pragma("unroll")                                                      \
        for (int ii = 0; ii < 2; ++ii)                                         \
            _Pragma("unroll")                                                  \
            for (int kk = 0; kk < 2; ++kk)                                     \
                af[ii][kk] = *reinterpret_cast<const short8*>(                 \
                    &(cA)[sw_off(wm * 128 + ((IQ) * 2 + ii) * 16 + r16,        \
                                 kk * 32 + g4 * 8)]);                          \
        if (LOADB) {                                                           \
            _Pragma("unroll")                                                  \
            for (int kk = 0; kk < 2; ++kk)                                     \
                _Pragma("unroll")                                              \
                for (int j = 0; j < 2; ++j) {                                  \
                    bg[kk][j] = *reinterpret_cast<const short8*>(              \
                        &(cB)[sw_off(wn * 32 + j * 16 + r16,                   \
                                     kk * 32 + g4 * 8)]);                      \
                    bu[kk][j] = *reinterpret_cast<const short8*>(              \
                        &(cB)[8192 + sw_off(wn * 32 + j * 16 + r16,            \
                                            kk * 32 + g4 * 8)]);               \
                }                                                              \
        }                                                                      \
        STAGE;                                                                 \
        VMC;                                                                   \
        if (LOADB) asm volatile("s_waitcnt lgkmcnt(8)" ::: "memory");          \
        __builtin_amdgcn_s_barrier();                                          \
        asm volatile("s_waitcnt lgkmcnt(0)" ::: "memory");                     \
        __builtin_amdgcn_sched_barrier(0);                                     \
        __builtin_amdgcn_s_setprio(1);                                         \
        _Pragma("unroll")                                                      \
        for (int ii = 0; ii < 2; ++ii)                                         \
            _Pragma("unroll")                                                  \
            for (int j = 0; j < 2; ++j) {                                      \
                accg[(IQ) * 2 + ii][j] = MFMA16(af[ii][0], bg[0][j],           \
                                                accg[(IQ) * 2 + ii][j]);       \
                accg[(IQ) * 2 + ii][j] = MFMA16(af[ii][1], bg[1][j],           \
                                                accg[(IQ) * 2 + ii][j]);       \
                accu[(IQ) * 2 + ii][j] = MFMA16(af[ii][0], bu[0][j],           \
                                                accu[(IQ) * 2 + ii][j]);       \
                accu[(IQ) * 2 + ii][j] = MFMA16(af[ii][1], bu[1][j],           \
                                                accu[(IQ) * 2 + ii][j]);       \
            }                                                                  \
        __builtin_amdgcn_s_setprio(0);                                         \
        __builtin_amdgcn_sched_barrier(0);                                     \
        __builtin_amdgcn_s_barrier();                                          \
    }

__global__ __launch_bounds__(512, 2)
void k_gateup(const __hip_bfloat16* __restrict__ X,
              const __hip_bfloat16* __restrict__ Wg,
              const __hip_bfloat16* __restrict__ Wu,
              __hip_bfloat16* __restrict__ H)
{
    extern __shared__ __hip_bfloat16 smem[];
    __hip_bfloat16* sA = smem;           // [2 buf][256 rows][64] = 64 KB
    __hip_bfloat16* sB = smem + 32768;   // [2 buf][G 128x64|U 128x64] = 64 KB

    const int tid  = threadIdx.x;
    const int lane = tid & 63;
    const int wid  = tid >> 6;
    const int wm = wid >> 2, wn = wid & 3;   // 2M x 4N waves
    const int r16 = lane & 15, g4 = lane >> 4;

    // T1: bijective XCD chunks (1376 = 8*172), m-fastest inside chunk
    const int bid = blockIdx.x;
    const int o = (bid & 7) * 172 + (bid >> 3);
    const int n0 = (o >> 4) * 128;       // 86 n-panels of 128
    const int m0 = (o & 15) * 256;       // 16 m-panels of 256

    const int ld = LDP;                  // padded stride for X/Wg/Wu
    const __hip_bfloat16* Ab = X  + (long)m0 * ld;
    const __hip_bfloat16* Gb = Wg + (long)n0 * ld;
    const __hip_bfloat16* Ub = Wu + (long)n0 * ld;
    const long h1 = (long)128 * ld;

    // prologue: A(tile0), B(tile0), B(tile1) — 12 loads, drain first 8
    stage_half(Ab,        ld, sA + 0,             tid);
    stage_half(Ab + h1,   ld, sA + 8192,          tid);
    stage_half(Gb,        ld, sB + 0,             tid);
    stage_half(Ub,        ld, sB + 8192,          tid);
    stage_half(Gb + 64,   ld, sB + 16384,         tid);
    stage_half(Ub + 64,   ld, sB + 16384 + 8192,  tid);
    asm volatile("s_waitcnt vmcnt(4)" ::: "memory");
    __builtin_amdgcn_s_barrier();

    f32x4 accg[8][2], accu[8][2];
#pragma unroll
    for (int i = 0; i < 8; ++i)
#pragma unroll
        for (int j = 0; j < 2; ++j) {
            accg[i][j] = (f32x4){0.f, 0.f, 0.f, 0.f};
            accu[i][j] = (f32x4){0.f, 0.f, 0.f, 0.f};
        }

    const int nk = D_MODEL >> 6;  // 64 K-tiles
    const int niter = nk >> 1;    // 32

    for (int it = 0; it < niter; ++it) {
        const bool pf = (it + 1 < niter);
        const long ko  = (long)(2 * it + 1) * 64;   // odd K-tile col offset
        const long kn2 = (long)(2 * it + 2) * 64;
        const long kn3 = (long)(2 * it + 3) * 64;
        short8 bg[2][2], bu[2][2];
        {   // ---- phases 1-4: K-tile 2it from buf0 ----
            const __hip_bfloat16* cA = sA;
            const __hip_bfloat16* cB = sB;
            FPHASE(cA, cB, 0, 1,
                stage_half(Ab + ko,      ld, sA + 16384,        tid), );
            FPHASE(cA, cB, 1, 0,
                stage_half(Ab + h1 + ko, ld, sA + 16384 + 8192, tid), );
            FPHASE(cA, cB, 2, 0,
                if (pf) stage_half(Gb + kn2, ld, sB + 0,    tid), );
            FPHASE(cA, cB, 3, 0,
                if (pf) stage_half(Ub + kn2, ld, sB + 8192, tid), VM4D);
        }
        {   // ---- phases 5-8: K-tile 2it+1 from buf1 ----
            const __hip_bfloat16* cA = sA + 16384;
            const __hip_bfloat16* cB = sB + 16384;
            FPHASE(cA, cB, 0, 1,
                if (pf) stage_half(Ab + kn2,      ld, sA + 0,    tid), );
            FPHASE(cA, cB, 1, 0,
                if (pf) stage_half(Ab + h1 + kn2, ld, sA + 8192, tid), );
            FPHASE(cA, cB, 2, 0,
                if (pf) stage_half(Gb + kn3, ld, sB + 16384,        tid), );
            FPHASE(cA, cB, 3, 0,
                if (pf) stage_half(Ub + kn3, ld, sB + 16384 + 8192, tid), VM4D);
        }
    }

    // epilogue: h = silu(g) * u
#pragma unroll
    for (int i = 0; i < 8; ++i)
#pragma unroll
        for (int j = 0; j < 2; ++j)
#pragma unroll
            for (int r = 0; r < 4; ++r) {
                long row = m0 + wm * 128 + i * 16 + g4 * 4 + r;
                long col = n0 + wn * 32 + j * 16 + r16;
                float g = accg[i][j][r];
                float u = accu[i][j][r];
                float s = g / (1.f + __expf(-g));
                H[row * D_FF + col] = __float2bfloat16(s * u);
            }
}

// ================= down proj: Y = H Wd^T (f32 out), 8-phase 2-tile ========
#define DPHASE(cA, cB, IQ, LOADB, STAGE, VMC)                                  \
    {                                                                          \
        short8 af[2][2];                                                       \
        _Pragma("unroll")                                                      \
        for (int ii = 0; ii < 2; ++ii)                                         \
            _Pragma("unroll")                                                  \
            for (int kk = 0; kk < 2; ++kk)                                     \
                af[ii][kk] = *reinterpret_cast<const short8*>(                 \
                    &(cA)[sw_off(wm * 128 + ((IQ) * 2 + ii) * 16 + r16,        \
                                 kk * 32 + g4 * 8)]);                          \
        if (LOADB) {                                                           \
            _Pragma("unroll")                                                  \
            for (int kk = 0; kk < 2; ++kk)                                     \
                _Pragma("unroll")                                              \
                for (int j = 0; j < 4; ++j)                                    \
                    bfr[kk][j] = *reinterpret_cast<const short8*>(             \
                        &(cB)[sw_off(wn * 64 + j * 16 + r16,                   \
                                     kk * 32 + g4 * 8)]);                      \
        }                                                                      \
        STAGE;                                                                 \
        VMC;                                                                   \
        if (LOADB) asm volatile("s_waitcnt lgkmcnt(8)" ::: "memory");          \
        __builtin_amdgcn_s_barrier();                                          \
        asm volatile("s_waitcnt lgkmcnt(0)" ::: "memory");                     \
        __builtin_amdgcn_sched_barrier(0);                                     \
        __builtin_amdgcn_s_setprio(1);                                         \
        _Pragma("unroll")                                                      \
        for (int ii = 0; ii < 2; ++ii)                                         \
            _Pragma("unroll")                                                  \
            for (int j = 0; j < 4; ++j) {                                      \
                acc[(IQ) * 2 + ii][j] = MFMA16(af[ii][0], bfr[0][j],           \
                                               acc[(IQ) * 2 + ii][j]);         \
                acc[(IQ) * 2 + ii][j] = MFMA16(af[ii][1], bfr[1][j],           \
                                               acc[(IQ) * 2 + ii][j]);         \
            }                                                                  \
        __builtin_amdgcn_s_setprio(0);                                         \
        __builtin_amdgcn_sched_barrier(0);                                     \
        __builtin_amdgcn_s_barrier();                                          \
    }

__global__ __launch_bounds__(512, 2)
void k_down(const __hip_bfloat16* __restrict__ A,
            const __hip_bfloat16* __restrict__ B,
            float* __restrict__ Y)
{
    extern __shared__ __hip_bfloat16 smem[];
    __hip_bfloat16* sA = smem;           // [2 buf][256][64]
    __hip_bfloat16* sB = smem + 32768;

    const int tid  = threadIdx.x;
    const int lane = tid & 63;
    const int wid  = tid >> 6;
    const int wm = wid >> 2, wn = wid & 3;
    const int r16 = lane & 15, g4 = lane >> 4;

    const int bid = blockIdx.x;          // 256 = 8*32
    const int o = (bid & 7) * 32 + (bid >> 3);
    const int n0 = (o >> 4) << 8;
    const int m0 = (o & 15) << 8;

    const int K = D_FF;
    const int N = D_MODEL;
    const __hip_bfloat16* Ab = A + (long)m0 * K;
    const __hip_bfloat16* Bb = B + (long)n0 * K;
    const long h1 = (long)128 * K;

    stage_half(Ab,            K, sA + 0,             tid);
    stage_half(Ab + h1,       K, sA + 8192,          tid);
    stage_half(Bb,            K, sB + 0,             tid);
    stage_half(Bb + h1,       K, sB + 8192,          tid);
    stage_half(Bb + 64,       K, sB + 16384,         tid);
    stage_half(Bb + h1 + 64,  K, sB + 16384 + 8192,  tid);
    asm volatile("s_waitcnt vmcnt(4)" ::: "memory");
    __builtin_amdgcn_s_barrier();

    f32x4 acc[8][4];
#pragma unroll
    for (int i = 0; i < 8; ++i)
#pragma unroll
        for (int j = 0; j < 4; ++j)
            acc[i][j] = (f32x4){0.f, 0.f, 0.f, 0.f};

    const int nk = K >> 6;        // 172
    const int niter = nk >> 1;    // 86

    for (int it = 0; it < niter; ++it) {
        const bool pf = (it + 1 < niter);
        const long ko  = (long)(2 * it + 1) * 64;
        const long kn2 = (long)(2 * it + 2) * 64;
        const long kn3 = (long)(2 * it + 3) * 64;
        {
            const __hip_bfloat16* cA = sA;
            const __hip_bfloat16* cB = sB;
            short8 bfr[2][4];
            DPHASE(cA, cB, 0, 1,
                stage_half(Ab + ko,      K, sA + 16384,        tid), );
            DPHASE(cA, cB, 1, 0,
                stage_half(Ab + h1 + ko, K, sA + 16384 + 8192, tid), );
            DPHASE(cA, cB, 2, 0,
                if (pf) stage_half(Bb + kn2,      K, sB + 0,    tid), );
            DPHASE(cA, cB, 3, 0,
                if (pf) stage_half(Bb + h1 + kn2, K, sB + 8192, tid), VM4D);
        }
        {
            const __hip_bfloat16* cA = sA + 16384;
            const __hip_bfloat16* cB = sB + 16384;
            short8 bfr[2][4];
            DPHASE(cA, cB, 0, 1,
                if (pf) stage_half(Ab + kn2,      K, sA + 0,    tid), );
            DPHASE(cA, cB, 1, 0,
                if (pf) stage_half(Ab + h1 + kn2, K, sA + 8192, tid), );
            DPHASE(cA, cB, 2, 0,
                if (pf) stage_half(Bb + kn3,      K, sB + 16384, tid), );
            DPHASE(cA, cB, 3, 0,
                if (pf) stage_half(Bb + h1 + kn3, K, sB + 16384 + 8192, tid), VM4D);
        }
    }

#pragma unroll
    for (int i = 0; i < 8; ++i)
#pragma unroll
        for (int j = 0; j < 4; ++j)
#pragma unroll
            for (int r = 0; r < 4; ++r) {
                long row = m0 + wm * 128 + i * 16 + g4 * 4 + r;
                long col = n0 + wn * 64 + j * 16 + r16;
                Y[row * N + col] = acc[i][j][r];
            }
}

extern "C" void kernel_launch(void* const* d_in, const int* in_sizes, int n_in,
                              void* d_out, int out_size, void* d_ws, size_t ws_size,
                              hipStream_t stream) {
    const float* x  = (const float*)d_in[0];
    const float* wg = (const float*)d_in[1];
    const float* wu = (const float*)d_in[2];
    const float* wd = (const float*)d_in[3];
    float* y = (float*)d_out;

    char* ws = (char*)d_ws;
    const size_t szX  = (size_t)NTOK * LDP * 2;       // padded X
    const size_t szWp = (size_t)D_FF * LDP * 2;       // padded Wg/Wu
    const size_t szWd = (size_t)D_MODEL * D_FF * 2;   // Wd (K=11008, unpadded)
    __hip_bfloat16* Xb  = (__hip_bfloat16*)(ws);
    __hip_bfloat16* Wgb = (__hip_bfloat16*)(ws + szX);
    __hip_bfloat16* Wub = (__hip_bfloat16*)(ws + szX + szWp);
    __hip_bfloat16* Wdb = (__hip_bfloat16*)(ws + szX + 2 * szWp);
    __hip_bfloat16* Hb  = (__hip_bfloat16*)(ws + szX + 2 * szWp + szWd);
    (void)ws_size; (void)out_size; (void)n_in; (void)in_sizes;

    const int SMEM = 131072;  // 128 KiB for both GEMMs
    hipFuncSetAttribute((const void*)k_gateup, hipFuncAttributeMaxDynamicSharedMemorySize, SMEM);
    hipFuncSetAttribute((const void*)k_down,   hipFuncAttributeMaxDynamicSharedMemorySize, SMEM);

    const int nXp = NTOK * 512;   // 512 chunks of 8 per K=4096 row
    const int nWp = D_FF * 512;
    const int nWd = D_MODEL * D_FF / 8;
    k_cvt_pad<<<(nXp + 255) / 256, 256, 0, stream>>>(x, Xb, nXp);
    k_cvt_pad<<<(nWp + 255) / 256, 256, 0, stream>>>(wg, Wgb, nWp);
    k_cvt_pad<<<(nWp + 255) / 256, 256, 0, stream>>>(wu, Wub, nWp);
    k_cvt<<<(nWd + 255) / 256, 256, 0, stream>>>(wd, Wdb, nWd);

    // fused: Hb = silu(X Wg^T) * (X Wu^T)
    k_gateup<<<1376, 512, SMEM, stream>>>(Xb, Wgb, Wub, Hb);
    // down:  Y = Hb Wd^T (f32 out)
    k_down<<<256, 512, SMEM, stream>>>(Hb, Wdb, y);
}

// Round 10
// 1003.544 us; speedup vs baseline: 2.7548x; 1.0417x over previous
//
#include <hip/hip_runtime.h>
#include <hip/hip_bf16.h>

#define D_MODEL 4096
#define D_FF    11008
#define NTOK    4096   // 2*2048 tokens

typedef __attribute__((ext_vector_type(8))) short short8;
typedef __attribute__((ext_vector_type(4))) float f32x4;

// ---------------- fp32 -> bf16 convert (8 elems/thread) ----------------
__global__ void k_cvt(const float* __restrict__ in, __hip_bfloat16* __restrict__ out, int n8) {
    int i = blockIdx.x * blockDim.x + threadIdx.x;
    if (i >= n8) return;
    const float4* p = (const float4*)in;
    float4 v0 = p[(size_t)i * 2];
    float4 v1 = p[(size_t)i * 2 + 1];
    float vals[8] = {v0.x, v0.y, v0.z, v0.w, v1.x, v1.y, v1.z, v1.w};
    short8 o;
#pragma unroll
    for (int j = 0; j < 8; ++j) {
        __hip_bfloat16 b = __float2bfloat16(vals[j]);
        o[j] = *reinterpret_cast<short*>(&b);
    }
    *reinterpret_cast<short8*>(out + (size_t)i * 8) = o;
}

// ---- stage one 128x64 bf16 half-tile via global_load_lds ----
// LDS dest linear; swizzle via permuted GLOBAL source chunk (rule #21):
// physical chunk p of row r holds logical chunk p ^ (r&7).
static __device__ __forceinline__ void stage_half(
    const __hip_bfloat16* g, int ld, __hip_bfloat16* lds, int tid)
{
#pragma unroll
    for (int s = 0; s < 2; ++s) {
        int ci = s * 512 + tid;            // 16B chunk 0..1023
        int r  = ci >> 3;                  // row 0..127
        int c  = (ci & 7) ^ (r & 7);       // logical chunk
        __builtin_amdgcn_global_load_lds(
            (const __attribute__((address_space(1))) void*)(g + (long)r * ld + c * 8),
            (__attribute__((address_space(3))) void*)(lds + ci * 8),
            16, 0, 0);
    }
}
// swizzled LDS read offset (row within 128-row half, kb = col, multiple of 8)
static __device__ __forceinline__ int sw_off(int row, int kb) {
    return row * 64 + ((((kb >> 3) ^ (row & 7))) << 3);
}

#define MFMA16(a, b, c) __builtin_amdgcn_mfma_f32_16x16x32_bf16(a, b, c, 0, 0, 0)
#define VM4D do { if (pf) asm volatile("s_waitcnt vmcnt(4)" ::: "memory");     \
                  else    asm volatile("s_waitcnt vmcnt(0)" ::: "memory"); } while (0)

// ============ fused gate+up: H = silu(X Wg^T) * (X Wu^T) ================
// 8-phase / 2 K-tile schedule; A = X (256x64 dbuf), B = [G|U] dbuf.
// A staged ph1-2/5-6, B staged ph3-4/7-8, vmcnt(4) at ph4/ph8.
#define FPHASE(cA, cB, IQ, LOADB, STAGE, VMC)                                  \
    {                                                                          \
        short8 af[2][2];                                                       \
        _Pragma("unroll")                                                      \
        for (int ii = 0; ii < 2; ++ii)                                         \
            _Pragma("unroll")                                                  \
            for (int kk = 0; kk < 2; ++kk)                                     \
                af[ii][kk] = *reinterpret_cast<const short8*>(                 \
                    &(cA)[sw_off(wm * 128 + ((IQ) * 2 + ii) * 16 + r16,        \
                                 kk * 32 + g4 * 8)]);                          \
        if (LOADB) {                                                           \
            _Pragma("unroll")                                                  \
            for (int kk = 0; kk < 2; ++kk)                                     \
                _Pragma("unroll")                                              \
                for (int j = 0; j < 2; ++j) {                                  \
                    bg[kk][j] = *reinterpret_cast<const short8*>(              \
                        &(cB)[sw_off(wn * 32 + j * 16 + r16,                   \
                                     kk * 32 + g4 * 8)]);                      \
                    bu[kk][j] = *reinterpret_cast<const short8*>(              \
                        &(cB)[8192 + sw_off(wn * 32 + j * 16 + r16,            \
                                            kk * 32 + g4 * 8)]);               \
                }                                                              \
        }                                                                      \
        STAGE;                                                                 \
        VMC;                                                                   \
        if (LOADB) asm volatile("s_waitcnt lgkmcnt(8)" ::: "memory");          \
        __builtin_amdgcn_s_barrier();                                          \
        asm volatile("s_waitcnt lgkmcnt(0)" ::: "memory");                     \
        __builtin_amdgcn_sched_barrier(0);                                     \
        __builtin_amdgcn_s_setprio(1);                                         \
        _Pragma("unroll")                                                      \
        for (int ii = 0; ii < 2; ++ii)                                         \
            _Pragma("unroll")                                                  \
            for (int j = 0; j < 2; ++j) {                                      \
                accg[(IQ) * 2 + ii][j] = MFMA16(af[ii][0], bg[0][j],           \
                                                accg[(IQ) * 2 + ii][j]);       \
                accg[(IQ) * 2 + ii][j] = MFMA16(af[ii][1], bg[1][j],           \
                                                accg[(IQ) * 2 + ii][j]);       \
                accu[(IQ) * 2 + ii][j] = MFMA16(af[ii][0], bu[0][j],           \
                                                accu[(IQ) * 2 + ii][j]);       \
                accu[(IQ) * 2 + ii][j] = MFMA16(af[ii][1], bu[1][j],           \
                                                accu[(IQ) * 2 + ii][j]);       \
            }                                                                  \
        __builtin_amdgcn_s_setprio(0);                                         \
        __builtin_amdgcn_sched_barrier(0);                                     \
        __builtin_amdgcn_s_barrier();                                          \
    }

// grid = 1376 GEMM blocks + 160 tail blocks that convert Wd f32->bf16
// (they dispatch last and fill the round-6 CU holes of the 5.375-round grid).
__global__ __launch_bounds__(512, 2)
void k_gateup(const __hip_bfloat16* __restrict__ X,
              const __hip_bfloat16* __restrict__ Wg,
              const __hip_bfloat16* __restrict__ Wu,
              __hip_bfloat16* __restrict__ H,
              const float* __restrict__ Wd32,
              __hip_bfloat16* __restrict__ Wdb)
{
    extern __shared__ __hip_bfloat16 smem[];
    __hip_bfloat16* sA = smem;           // [2 buf][256 rows][64] = 64 KB
    __hip_bfloat16* sB = smem + 32768;   // [2 buf][G 128x64|U 128x64] = 64 KB

    const int tid = threadIdx.x;
    const int bid = blockIdx.x;

    if (bid >= 1376) {                   // ---- fused Wd cvt tail ----
        const long total8 = (long)D_MODEL * D_FF / 8;
        const long stride = 160L * 512;
        for (long i = (long)(bid - 1376) * 512 + tid; i < total8; i += stride) {
            const float4* p = (const float4*)(Wd32 + i * 8);
            float4 v0 = p[0], v1 = p[1];
            float vals[8] = {v0.x, v0.y, v0.z, v0.w, v1.x, v1.y, v1.z, v1.w};
            short8 oo;
#pragma unroll
            for (int j = 0; j < 8; ++j) {
                __hip_bfloat16 b = __float2bfloat16(vals[j]);
                oo[j] = *reinterpret_cast<short*>(&b);
            }
            *reinterpret_cast<short8*>(Wdb + i * 8) = oo;
        }
        return;
    }

    const int lane = tid & 63;
    const int wid  = tid >> 6;
    const int wm = wid >> 2, wn = wid & 3;   // 2M x 4N waves
    const int r16 = lane & 15, g4 = lane >> 4;

    // X-resident mapping: each XCD (bid&7) pins 2 X m-panels; n advances
    // every 2 blocks so each W panel has 2 concurrent readers (1 L2 fetch),
    // and the XCD's 2 A-panels (4.3MB) stay L2/L3-hot across all 86 n.
    const int xcd = bid & 7;
    const int o   = bid >> 3;            // 0..171
    const int n0 = (o >> 1) * 128;
    const int m0 = (xcd * 2 + (o & 1)) * 256;

    const int K = D_MODEL;
    const __hip_bfloat16* Ab = X  + (long)m0 * K;
    const __hip_bfloat16* Gb = Wg + (long)n0 * K;
    const __hip_bfloat16* Ub = Wu + (long)n0 * K;
    const long h1 = (long)128 * K;

    // prologue: A(tile0), B(tile0), B(tile1) — 12 loads, drain first 8
    stage_half(Ab,        K, sA + 0,             tid);
    stage_half(Ab + h1,   K, sA + 8192,          tid);
    stage_half(Gb,        K, sB + 0,             tid);
    stage_half(Ub,        K, sB + 8192,          tid);
    stage_half(Gb + 64,   K, sB + 16384,         tid);
    stage_half(Ub + 64,   K, sB + 16384 + 8192,  tid);
    asm volatile("s_waitcnt vmcnt(4)" ::: "memory");
    __builtin_amdgcn_s_barrier();

    f32x4 accg[8][2], accu[8][2];
#pragma unroll
    for (int i = 0; i < 8; ++i)
#pragma unroll
        for (int j = 0; j < 2; ++j) {
            accg[i][j] = (f32x4){0.f, 0.f, 0.f, 0.f};
            accu[i][j] = (f32x4){0.f, 0.f, 0.f, 0.f};
        }

    const int nk = D_MODEL >> 6;  // 64 K-tiles
    const int niter = nk >> 1;    // 32

    for (int it = 0; it < niter; ++it) {
        const bool pf = (it + 1 < niter);
        const long ko  = (long)(2 * it + 1) * 64;
        const long kn2 = (long)(2 * it + 2) * 64;
        const long kn3 = (long)(2 * it + 3) * 64;
        short8 bg[2][2], bu[2][2];
        {   // ---- phases 1-4: K-tile 2it from buf0 ----
            const __hip_bfloat16* cA = sA;
            const __hip_bfloat16* cB = sB;
            FPHASE(cA, cB, 0, 1,
                stage_half(Ab + ko,      K, sA + 16384,        tid), );
            FPHASE(cA, cB, 1, 0,
                stage_half(Ab + h1 + ko, K, sA + 16384 + 8192, tid), );
            FPHASE(cA, cB, 2, 0,
                if (pf) stage_half(Gb + kn2, K, sB + 0,    tid), );
            FPHASE(cA, cB, 3, 0,
                if (pf) stage_half(Ub + kn2, K, sB + 8192, tid), VM4D);
        }
        {   // ---- phases 5-8: K-tile 2it+1 from buf1 ----
            const __hip_bfloat16* cA = sA + 16384;
            const __hip_bfloat16* cB = sB + 16384;
            FPHASE(cA, cB, 0, 1,
                if (pf) stage_half(Ab + kn2,      K, sA + 0,    tid), );
            FPHASE(cA, cB, 1, 0,
                if (pf) stage_half(Ab + h1 + kn2, K, sA + 8192, tid), );
            FPHASE(cA, cB, 2, 0,
                if (pf) stage_half(Gb + kn3, K, sB + 16384,        tid), );
            FPHASE(cA, cB, 3, 0,
                if (pf) stage_half(Ub + kn3, K, sB + 16384 + 8192, tid), VM4D);
        }
    }

    // epilogue: h = silu(g) * u
#pragma unroll
    for (int i = 0; i < 8; ++i)
#pragma unroll
        for (int j = 0; j < 2; ++j)
#pragma unroll
            for (int r = 0; r < 4; ++r) {
                long row = m0 + wm * 128 + i * 16 + g4 * 4 + r;
                long col = n0 + wn * 32 + j * 16 + r16;
                float g = accg[i][j][r];
                float u = accu[i][j][r];
                float s = g / (1.f + __expf(-g));
                H[row * D_FF + col] = __float2bfloat16(s * u);
            }
}

// ================= down proj: Y = H Wd^T (f32 out), 8-phase 2-tile ========
#define DPHASE(cA, cB, IQ, LOADB, STAGE, VMC)                                  \
    {                                                                          \
        short8 af[2][2];                                                       \
        _Pragma("unroll")                                                      \
        for (int ii = 0; ii < 2; ++ii)                                         \
            _Pragma("unroll")                                                  \
            for (int kk = 0; kk < 2; ++kk)                                     \
                af[ii][kk] = *reinterpret_cast<const short8*>(                 \
                    &(cA)[sw_off(wm * 128 + ((IQ) * 2 + ii) * 16 + r16,        \
                                 kk * 32 + g4 * 8)]);                          \
        if (LOADB) {                                                           \
            _Pragma("unroll")                                                  \
            for (int kk = 0; kk < 2; ++kk)                                     \
                _Pragma("unroll")                                              \
                for (int j = 0; j < 4; ++j)                                    \
                    bfr[kk][j] = *reinterpret_cast<const short8*>(             \
                        &(cB)[sw_off(wn * 64 + j * 16 + r16,                   \
                                     kk * 32 + g4 * 8)]);                      \
        }                                                                      \
        STAGE;                                                                 \
        VMC;                                                                   \
        if (LOADB) asm volatile("s_waitcnt lgkmcnt(8)" ::: "memory");          \
        __builtin_amdgcn_s_barrier();                                          \
        asm volatile("s_waitcnt lgkmcnt(0)" ::: "memory");                     \
        __builtin_amdgcn_sched_barrier(0);                                     \
        __builtin_amdgcn_s_setprio(1);                                         \
        _Pragma("unroll")                                                      \
        for (int ii = 0; ii < 2; ++ii)                                         \
            _Pragma("unroll")                                                  \
            for (int j = 0; j < 4; ++j) {                                      \
                acc[(IQ) * 2 + ii][j] = MFMA16(af[ii][0], bfr[0][j],           \
                                               acc[(IQ) * 2 + ii][j]);         \
                acc[(IQ) * 2 + ii][j] = MFMA16(af[ii][1], bfr[1][j],           \
                                               acc[(IQ) * 2 + ii][j]);         \
            }                                                                  \
        __builtin_amdgcn_s_setprio(0);                                         \
        __builtin_amdgcn_sched_barrier(0);                                     \
        __builtin_amdgcn_s_barrier();                                          \
    }

__global__ __launch_bounds__(512, 2)
void k_down(const __hip_bfloat16* __restrict__ A,
            const __hip_bfloat16* __restrict__ B,
            float* __restrict__ Y)
{
    extern __shared__ __hip_bfloat16 smem[];
    __hip_bfloat16* sA = smem;           // [2 buf][256][64]
    __hip_bfloat16* sB = smem + 32768;

    const int tid  = threadIdx.x;
    const int lane = tid & 63;
    const int wid  = tid >> 6;
    const int wm = wid >> 2, wn = wid & 3;
    const int r16 = lane & 15, g4 = lane >> 4;

    const int bid = blockIdx.x;          // 256 = 8*32
    const int o = (bid & 7) * 32 + (bid >> 3);
    const int n0 = (o >> 4) << 8;
    const int m0 = (o & 15) << 8;

    const int K = D_FF;
    const int N = D_MODEL;
    const __hip_bfloat16* Ab = A + (long)m0 * K;
    const __hip_bfloat16* Bb = B + (long)n0 * K;
    const long h1 = (long)128 * K;

    stage_half(Ab,            K, sA + 0,             tid);
    stage_half(Ab + h1,       K, sA + 8192,          tid);
    stage_half(Bb,            K, sB + 0,             tid);
    stage_half(Bb + h1,       K, sB + 8192,          tid);
    stage_half(Bb + 64,       K, sB + 16384,         tid);
    stage_half(Bb + h1 + 64,  K, sB + 16384 + 8192,  tid);
    asm volatile("s_waitcnt vmcnt(4)" ::: "memory");
    __builtin_amdgcn_s_barrier();

    f32x4 acc[8][4];
#pragma unroll
    for (int i = 0; i < 8; ++i)
#pragma unroll
        for (int j = 0; j < 4; ++j)
            acc[i][j] = (f32x4){0.f, 0.f, 0.f, 0.f};

    const int nk = K >> 6;        // 172
    const int niter = nk >> 1;    // 86

    for (int it = 0; it < niter; ++it) {
        const bool pf = (it + 1 < niter);
        const long ko  = (long)(2 * it + 1) * 64;
        const long kn2 = (long)(2 * it + 2) * 64;
        const long kn3 = (long)(2 * it + 3) * 64;
        {
            const __hip_bfloat16* cA = sA;
            const __hip_bfloat16* cB = sB;
            short8 bfr[2][4];
            DPHASE(cA, cB, 0, 1,
                stage_half(Ab + ko,      K, sA + 16384,        tid), );
            DPHASE(cA, cB, 1, 0,
                stage_half(Ab + h1 + ko, K, sA + 16384 + 8192, tid), );
            DPHASE(cA, cB, 2, 0,
                if (pf) stage_half(Bb + kn2,      K, sB + 0,    tid), );
            DPHASE(cA, cB, 3, 0,
                if (pf) stage_half(Bb + h1 + kn2, K, sB + 8192, tid), VM4D);
        }
        {
            const __hip_bfloat16* cA = sA + 16384;
            const __hip_bfloat16* cB = sB + 16384;
            short8 bfr[2][4];
            DPHASE(cA, cB, 0, 1,
                if (pf) stage_half(Ab + kn2,      K, sA + 0,    tid), );
            DPHASE(cA, cB, 1, 0,
                if (pf) stage_half(Ab + h1 + kn2, K, sA + 8192, tid), );
            DPHASE(cA, cB, 2, 0,
                if (pf) stage_half(Bb + kn3,      K, sB + 16384, tid), );
            DPHASE(cA, cB, 3, 0,
                if (pf) stage_half(Bb + h1 + kn3, K, sB + 16384 + 8192, tid), VM4D);
        }
    }

#pragma unroll
    for (int i = 0; i < 8; ++i)
#pragma unroll
        for (int j = 0; j < 4; ++j)
#pragma unroll
            for (int r = 0; r < 4; ++r) {
                long row = m0 + wm * 128 + i * 16 + g4 * 4 + r;
                long col = n0 + wn * 64 + j * 16 + r16;
                Y[row * N + col] = acc[i][j][r];
            }
}

extern "C" void kernel_launch(void* const* d_in, const int* in_sizes, int n_in,
                              void* d_out, int out_size, void* d_ws, size_t ws_size,
                              hipStream_t stream) {
    const float* x  = (const float*)d_in[0];
    const float* wg = (const float*)d_in[1];
    const float* wu = (const float*)d_in[2];
    const float* wd = (const float*)d_in[3];
    float* y = (float*)d_out;

    char* ws = (char*)d_ws;
    const size_t szX = (size_t)NTOK * D_MODEL * 2;
    const size_t szW = (size_t)D_FF * D_MODEL * 2;
    __hip_bfloat16* Xb  = (__hip_bfloat16*)(ws);
    __hip_bfloat16* Wgb = (__hip_bfloat16*)(ws + szX);
    __hip_bfloat16* Wub = (__hip_bfloat16*)(ws + szX + szW);
    __hip_bfloat16* Wdb = (__hip_bfloat16*)(ws + szX + 2 * szW);
    __hip_bfloat16* Hb  = (__hip_bfloat16*)(ws + szX + 3 * szW);
    (void)ws_size; (void)out_size; (void)n_in; (void)in_sizes;

    const int SMEM = 131072;  // 128 KiB for both GEMMs
    hipFuncSetAttribute((const void*)k_gateup, hipFuncAttributeMaxDynamicSharedMemorySize, SMEM);
    hipFuncSetAttribute((const void*)k_down,   hipFuncAttributeMaxDynamicSharedMemorySize, SMEM);

    const int nX = NTOK * D_MODEL / 8;
    const int nW = D_FF * D_MODEL / 8;
    k_cvt<<<(nX + 255) / 256, 256, 0, stream>>>(x, Xb, nX);
    k_cvt<<<(nW + 255) / 256, 256, 0, stream>>>(wg, Wgb, nW);
    k_cvt<<<(nW + 255) / 256, 256, 0, stream>>>(wu, Wub, nW);

    // fused: Hb = silu(X Wg^T) * (X Wu^T); tail blocks (1376..1535) convert Wd
    k_gateup<<<1536, 512, SMEM, stream>>>(Xb, Wgb, Wub, Hb, wd, Wdb);
    // down:  Y = Hb Wd^T (f32 out)
    k_down<<<256, 512, SMEM, stream>>>(Hb, Wdb, y);
}